// Round 3
// baseline (159.221 us; speedup 1.0000x reference)
//
#include <hip/hip_runtime.h>
#include <math.h>

#define ALPHA   0.99f
#define ONE_M   0.01f     // 1 - ALPHA
#define T_LEN   4000
#define F_DIM   64
#define NCHUNK  125
#define CHUNK_L 32        // T_LEN / NCHUNK
#define FH      32        // features per block (F split across 2 blocks)
#define NG      8         // float4 groups per block = FH/4
#define NTHREADS (NCHUNK * NG)   // 1000 (16 waves, last wave 40/64 active)
#define PF      8         // prefetch depth (float4 loads in flight per thread)

typedef float f32x4 __attribute__((ext_vector_type(4)));

// Exact chunked scan, per (b, f):
//   mu_L  = a^L mu_0 + m_L                     (m: EMA of x within chunk)
//   var_L = a^L var_0 + SP + c2*SU*mu_0 + R*mu_0^2
//   SP = EMA of u^2, SU = sum of u (u = x - m), c2 = -2(1-a)a^L, R = a^{L+1}(1-a^L)
__global__ __launch_bounds__(1024, 8)
void erbnorm_kernel(const float* __restrict__ x, float* __restrict__ out, float aL) {
    const int blk = blockIdx.x;
    const int b   = blk >> 1;
    const int f0  = (blk & 1) * FH;
    const int tid = threadIdx.x;
    const int c   = tid >> 3;          // chunk 0..124
    const int g   = tid & 7;           // float4 group 0..7

    __shared__ float s_m [NCHUNK][FH];   // m  -> entering mu (in-place after combine)
    __shared__ float s_sp[NCHUNK][FH];   // SP -> entering var
    __shared__ float s_su[NCHUNK][FH];   // SU

    const size_t base = ((size_t)b * T_LEN + (size_t)c * CHUNK_L) * F_DIM + f0 + g * 4;
    const float* xp = x + base;

    // ---- pass 1: per-chunk transition coefficients (4 features per thread) ----
    {
        f32x4 m = 0.f, sp = 0.f, su = 0.f;
        for (int ii = 0; ii < CHUNK_L; ii += PF) {
            f32x4 v[PF];
#pragma unroll
            for (int j = 0; j < PF; ++j)
                v[j] = *(const f32x4*)(xp + (size_t)(ii + j) * F_DIM);
#pragma unroll
            for (int j = 0; j < PF; ++j) {
                f32x4 xi = v[j];
                m = ALPHA * m + ONE_M * xi;
                f32x4 u = xi - m;
                sp = ALPHA * sp + ONE_M * (u * u);
                su = su + u;
            }
        }
        *(f32x4*)&s_m [c][g * 4] = m;
        *(f32x4*)&s_sp[c][g * 4] = sp;
        *(f32x4*)&s_su[c][g * 4] = su;
    }
    __syncthreads();

    // ---- combine: serial chain over 125 chunks, one thread per feature ----
    if (tid < FH) {
        const float step = -30.f / 63.f;
        const int   fg   = f0 + tid;
        float mu  = -60.f + (float)fg * step;
        float var = 1600.f;
        const float R  = ALPHA * aL * (1.f - aL);   // a^(L+1)(1-a^L)
        const float c2 = -2.f * ONE_M * aL;         // -2(1-a)a^L
        for (int cc = 0; cc < NCHUNK; ++cc) {
            float m  = s_m [cc][tid];
            float sp = s_sp[cc][tid];
            float su = s_su[cc][tid];
            s_m [cc][tid] = mu;                     // entering state for pass 2
            s_sp[cc][tid] = var;
            float mu_n = aL * mu + m;
            var = aL * var + sp + (c2 * su) * mu + R * mu * mu;
            mu = mu_n;
        }
    }
    __syncthreads();

    // ---- pass 2: replay with exact entering state, emit outputs ----
    {
        f32x4 mu  = *(const f32x4*)&s_m [c][g * 4];
        f32x4 var = *(const f32x4*)&s_sp[c][g * 4];
        float* op = out + base;
        for (int ii = 0; ii < CHUNK_L; ii += PF) {
            f32x4 v[PF];
#pragma unroll
            for (int j = 0; j < PF; ++j)
                v[j] = *(const f32x4*)(xp + (size_t)(ii + j) * F_DIM);
#pragma unroll
            for (int j = 0; j < PF; ++j) {
                f32x4 xi = v[j];
                mu = ALPHA * mu + ONE_M * xi;
                f32x4 d = xi - mu;
                var = ALPHA * var + ONE_M * (d * d);
                f32x4 o;
                o[0] = d[0] * __builtin_amdgcn_rsqf(var[0]);
                o[1] = d[1] * __builtin_amdgcn_rsqf(var[1]);
                o[2] = d[2] * __builtin_amdgcn_rsqf(var[2]);
                o[3] = d[3] * __builtin_amdgcn_rsqf(var[3]);
                *(f32x4*)(op + (size_t)(ii + j) * F_DIM) = o;
            }
        }
    }
}

extern "C" void kernel_launch(void* const* d_in, const int* in_sizes, int n_in,
                              void* d_out, int out_size, void* d_ws, size_t ws_size,
                              hipStream_t stream) {
    const float* x = (const float*)d_in[0];
    float* out = (float*)d_out;
    const float aL = (float)pow(0.99, (double)CHUNK_L);  // a^L
    hipLaunchKernelGGL(erbnorm_kernel, dim3(512), dim3(NTHREADS), 0, stream,
                       x, out, aL);
}

// Round 4
// 156.692 us; speedup vs baseline: 1.0161x; 1.0161x over previous
//
#include <hip/hip_runtime.h>
#include <math.h>

#define ALPHA   0.99f
#define ONE_M   0.01f     // 1 - ALPHA
#define T_LEN   4000
#define F_DIM   64
#define NCHUNK  50
#define CHUNK_L 80        // T_LEN / NCHUNK
#define NG      16        // float4 groups per row = F_DIM/4  (full 256B rows!)
#define NTHREADS (NCHUNK * NG)   // 800
#define PF      8         // prefetch depth (float4 loads in flight per thread)

typedef float f32x4 __attribute__((ext_vector_type(4)));

// Exact chunked scan, per (b, f):
//   mu_L  = a^L mu_0 + m_L                     (m: EMA of x within chunk)
//   var_L = a^L var_0 + SP + c2*SU*mu_0 + R*mu_0^2
//   SP = EMA of u^2, SU = sum of u (u = x - m), c2 = -2(1-a)a^L, R = a^{L+1}(1-a^L)
//
// One block per batch row b: each wave-load covers 4 FULL contiguous 256B
// rows (16 lanes x 16B), maximizing DRAM page utilization.
__global__ __launch_bounds__(NTHREADS, 3)
void erbnorm_kernel(const float* __restrict__ x, float* __restrict__ out, float aL) {
    const int b   = blockIdx.x;
    const int tid = threadIdx.x;
    const int c   = tid >> 4;          // chunk 0..49
    const int g   = tid & 15;          // float4 group 0..15

    __shared__ float s_m [NCHUNK][F_DIM];   // m  -> entering mu (after combine)
    __shared__ float s_sp[NCHUNK][F_DIM];   // SP -> entering var
    __shared__ float s_su[NCHUNK][F_DIM];   // SU

    const size_t base = ((size_t)b * T_LEN + (size_t)c * CHUNK_L) * F_DIM + g * 4;
    const float* xp = x + base;

    // ---- pass 1: per-chunk transition coefficients (4 features per thread) ----
    {
        f32x4 m = 0.f, sp = 0.f, su = 0.f;
        for (int ii = 0; ii < CHUNK_L; ii += PF) {
            f32x4 v[PF];
#pragma unroll
            for (int j = 0; j < PF; ++j)
                v[j] = *(const f32x4*)(xp + (size_t)(ii + j) * F_DIM);
#pragma unroll
            for (int j = 0; j < PF; ++j) {
                f32x4 xi = v[j];
                m = ALPHA * m + ONE_M * xi;
                f32x4 u = xi - m;
                sp = ALPHA * sp + ONE_M * (u * u);
                su = su + u;
            }
        }
        *(f32x4*)&s_m [c][g * 4] = m;
        *(f32x4*)&s_sp[c][g * 4] = sp;
        *(f32x4*)&s_su[c][g * 4] = su;
    }
    __syncthreads();

    // ---- combine: serial chain over 50 chunks, one thread per feature ----
    if (tid < F_DIM) {
        const float step = -30.f / 63.f;
        float mu  = -60.f + (float)tid * step;
        float var = 1600.f;
        const float R  = ALPHA * aL * (1.f - aL);   // a^(L+1)(1-a^L)
        const float c2 = -2.f * ONE_M * aL;         // -2(1-a)a^L
        for (int cc = 0; cc < NCHUNK; ++cc) {
            float m  = s_m [cc][tid];
            float sp = s_sp[cc][tid];
            float su = s_su[cc][tid];
            s_m [cc][tid] = mu;                     // entering state for pass 2
            s_sp[cc][tid] = var;
            float mu_n = aL * mu + m;
            var = aL * var + sp + (c2 * su) * mu + R * mu * mu;
            mu = mu_n;
        }
    }
    __syncthreads();

    // ---- pass 2: replay with exact entering state, emit outputs ----
    {
        f32x4 mu  = *(const f32x4*)&s_m [c][g * 4];
        f32x4 var = *(const f32x4*)&s_sp[c][g * 4];
        float* op = out + base;
        for (int ii = 0; ii < CHUNK_L; ii += PF) {
            f32x4 v[PF];
#pragma unroll
            for (int j = 0; j < PF; ++j)
                v[j] = *(const f32x4*)(xp + (size_t)(ii + j) * F_DIM);
#pragma unroll
            for (int j = 0; j < PF; ++j) {
                f32x4 xi = v[j];
                mu = ALPHA * mu + ONE_M * xi;
                f32x4 d = xi - mu;
                var = ALPHA * var + ONE_M * (d * d);
                f32x4 o;
                o[0] = d[0] * __builtin_amdgcn_rsqf(var[0]);
                o[1] = d[1] * __builtin_amdgcn_rsqf(var[1]);
                o[2] = d[2] * __builtin_amdgcn_rsqf(var[2]);
                o[3] = d[3] * __builtin_amdgcn_rsqf(var[3]);
                *(f32x4*)(op + (size_t)(ii + j) * F_DIM) = o;
            }
        }
    }
}

extern "C" void kernel_launch(void* const* d_in, const int* in_sizes, int n_in,
                              void* d_out, int out_size, void* d_ws, size_t ws_size,
                              hipStream_t stream) {
    const float* x = (const float*)d_in[0];
    float* out = (float*)d_out;
    const float aL = (float)pow(0.99, (double)CHUNK_L);  // a^L
    hipLaunchKernelGGL(erbnorm_kernel, dim3(256), dim3(NTHREADS), 0, stream,
                       x, out, aL);
}